// Round 10
// baseline (763.743 us; speedup 1.0000x reference)
//
#include <hip/hip_runtime.h>
#include <cstddef>

static constexpr int NN = 50000;
static constexpr int NE = 600000;
static constexpr int NB = (NN + 255) / 256;   // 196 scan blocks

using f32x4 = __attribute__((ext_vector_type(4))) float;
using s16x8 = __attribute__((ext_vector_type(8))) short;

// ---------------- bf16 helpers (manual, RNE) ----------------
__device__ inline float bf2f(unsigned short u) {
    return __uint_as_float(((unsigned)u) << 16);
}
__device__ inline unsigned short f2bf(float f) {
    unsigned u = __float_as_uint(f);
    unsigned r = u + 0x7fffu + ((u >> 16) & 1u);
    return (unsigned short)(r >> 16);
}
__device__ inline float lof(unsigned u) { return __uint_as_float(u << 16); }
__device__ inline float hif(unsigned u) { return __uint_as_float(u & 0xffff0000u); }
__device__ inline unsigned packbf(float a, float b) {
    return (unsigned)f2bf(a) | ((unsigned)f2bf(b) << 16);
}

// ---------------- zero deg + weight transpose/bf16 prepass (fused) ----------
__global__ __launch_bounds__(256)
void zero_wprep_k(int* __restrict__ deg,
                  const float* __restrict__ w1_rel, const float* __restrict__ w1_root,
                  const float* __restrict__ w2_rel, const float* __restrict__ w2_root,
                  const float* __restrict__ w_mu,   const float* __restrict__ w_ls,
                  unsigned short* __restrict__ wt1, unsigned short* __restrict__ wt2,
                  unsigned short* __restrict__ wt3)
{
    int i = blockIdx.x * 256 + threadIdx.x;
    if (i < NN) deg[i] = 0;
    if (i < 24576) {                       // WT1: K=128, N=192
        int k = i / 192, n = i % 192;
        float v = (n < 96) ? w1_rel[k * 96 + n] : w1_root[k * 96 + (n - 96)];
        wt1[n * 128 + k] = f2bf(v);
    } else if (i < 36864) {                // WT2: K=96, N=128
        int j = i - 24576;
        int k = j / 128, n = j % 128;
        float v = (n < 64) ? w2_rel[k * 64 + n] : w2_root[k * 64 + (n - 64)];
        wt2[n * 96 + k] = f2bf(v);
    } else if (i < 40960) {                // WT3: K=64, N=64
        int j = i - 36864;
        int k = j / 64, n = j % 64;
        float v = (n < 32) ? w_mu[k * 32 + n] : w_ls[k * 32 + (n - 32)];
        wt3[n * 64 + k] = f2bf(v);
    }
}

// ---------------- degree count ----------------
__global__ __launch_bounds__(256)
void count_deg_k(const int* __restrict__ dstv, int* __restrict__ deg) {
    int e = blockIdx.x * 256 + threadIdx.x;
    if (e < NE) atomicAdd(&deg[dstv[e]], 1);
}

// ---------------- scan: per-block reduce -> partial ----------------
__global__ __launch_bounds__(256)
void scan_reduce_k(const int* __restrict__ deg, int* __restrict__ partial) {
    __shared__ int buf[256];
    int i = blockIdx.x * 256 + threadIdx.x;
    buf[threadIdx.x] = (i < NN) ? deg[i] : 0;
    __syncthreads();
    #pragma unroll
    for (int off = 128; off > 0; off >>= 1) {
        if (threadIdx.x < off) buf[threadIdx.x] += buf[threadIdx.x + off];
        __syncthreads();
    }
    if (threadIdx.x == 0) partial[blockIdx.x] = buf[0];
}

// ---------------- scan final: each block scans partials itself ----------------
__global__ __launch_bounds__(256)
void scan_final2_k(const int* __restrict__ deg, const int* __restrict__ partial,
                   int* __restrict__ row_start, int* __restrict__ cursor,
                   float* __restrict__ dinv) {
    __shared__ int pb[256], po[256], buf[256];
    int t = threadIdx.x;
    int pv = (t < NB) ? partial[t] : 0;
    pb[t] = pv; po[t] = pv;
    __syncthreads();
    #pragma unroll
    for (int off = 1; off < 256; off <<= 1) {
        int tv = (t >= off) ? pb[t - off] : 0;
        __syncthreads();
        pb[t] += tv;
        __syncthreads();
    }
    int i = blockIdx.x * 256 + t;
    int v = (i < NN) ? deg[i] : 0;
    buf[t] = v;
    __syncthreads();
    #pragma unroll
    for (int off = 1; off < 256; off <<= 1) {
        int tv = (t >= off) ? buf[t - off] : 0;
        __syncthreads();
        buf[t] += tv;
        __syncthreads();
    }
    int blkoff = pb[blockIdx.x] - po[blockIdx.x];   // exclusive offset of this block
    if (i < NN) {
        int pos = blkoff + buf[t] - v;
        row_start[i] = pos;
        cursor[i] = pos;
        dinv[i] = rsqrtf((float)v + 1.0f);          // +1 self-loop
    }
    if (blockIdx.x == 0 && t == 0) row_start[NN] = pb[NB - 1];   // == NE
}

// ---------------- CSR fill ----------------
__global__ __launch_bounds__(256)
void fill_k(const int* __restrict__ srcv, const int* __restrict__ dstv,
            int* __restrict__ cursor, int* __restrict__ csr)
{
    int e = blockIdx.x * 256 + threadIdx.x;
    if (e < NE) {
        int pos = atomicAdd(&cursor[dstv[e]], 1);
        csr[pos] = srcv[e];
    }
}

// ---------------- MFMA GEMM (layer 1, dense input) ----------------
template<int K, int NH, bool XB, bool SCALE>
__global__ __launch_bounds__(256)
void gemm_mfma(const void* __restrict__ Xv,
               const unsigned short* __restrict__ WT,
               const float* __restrict__ biasB,
               const float* __restrict__ scale,
               unsigned short* __restrict__ out0,
               unsigned short* __restrict__ out1)
{
    constexpr int KQ = K / 4;
    constexpr int PB = K * 2;
    constexpr int KS = K / 32;
    constexpr int NT = NH / 16;
    __shared__ short lds[(128 + NH) * K];
    char* ldsb = (char*)lds;
    const int tid = threadIdx.x;
    const int blk = blockIdx.x;
    const int half = blockIdx.y;

    const unsigned short* wt = WT + (size_t)half * NH * K;
    unsigned short* outp = half ? out1 : out0;

    #pragma unroll
    for (int it = 0; it < KQ / 2; ++it) {
        int idx = it * 256 + tid;
        int r = idx / KQ, c4 = idx % KQ;
        int node = blk * 128 + r; if (node >= NN) node = NN - 1;
        uint2 p;
        if (XB) {
            p = *(const uint2*)((const unsigned short*)Xv + (size_t)node * K + c4 * 4);
        } else {
            float4 v = *(const float4*)((const float*)Xv + (size_t)node * K + c4 * 4);
            p.x = packbf(v.x, v.y); p.y = packbf(v.z, v.w);
        }
        unsigned byte = (unsigned)(r * PB + c4 * 8) ^ ((unsigned)(r & 7) << 4);
        *(uint2*)(ldsb + byte) = p;
    }
    #pragma unroll
    for (int it = 0; it < NH * KQ / 256; ++it) {
        int idx = it * 256 + tid;
        int n = idx / KQ, c4 = idx % KQ;
        uint2 p = *(const uint2*)(wt + (size_t)n * K + c4 * 4);
        int pr = 128 + n;
        unsigned byte = (unsigned)(pr * PB + c4 * 8) ^ ((unsigned)(pr & 7) << 4);
        *(uint2*)(ldsb + byte) = p;
    }
    __syncthreads();

    const int wv = tid >> 6, lane = tid & 63;
    const int r15 = lane & 15, g = lane >> 4;

    s16x8 afr[2][KS];
    #pragma unroll
    for (int ms = 0; ms < 2; ++ms) {
        #pragma unroll
        for (int ks = 0; ks < KS; ++ks) {
            int r = wv * 32 + ms * 16 + r15;
            unsigned byte = (unsigned)(r * PB + ks * 64 + g * 16) ^ ((unsigned)(r & 7) << 4);
            afr[ms][ks] = *(const s16x8*)(ldsb + byte);
        }
    }

    #pragma unroll
    for (int nt = 0; nt < NT; ++nt) {
        s16x8 bfr[KS];
        #pragma unroll
        for (int ks = 0; ks < KS; ++ks) {
            int pr = 128 + nt * 16 + r15;
            unsigned byte = (unsigned)(pr * PB + ks * 64 + g * 16) ^ ((unsigned)(pr & 7) << 4);
            bfr[ks] = *(const s16x8*)(ldsb + byte);
        }
        int c = nt * 16 + r15;
        float bias = (half && biasB) ? biasB[c] : 0.f;
        #pragma unroll
        for (int ms = 0; ms < 2; ++ms) {
            f32x4 acc = {0.f, 0.f, 0.f, 0.f};
            #pragma unroll
            for (int ks = 0; ks < KS; ++ks)
                acc = __builtin_amdgcn_mfma_f32_16x16x32_bf16(afr[ms][ks], bfr[ks], acc, 0, 0, 0);
            int nb = blk * 128 + wv * 32 + ms * 16 + g * 4;
            #pragma unroll
            for (int rg = 0; rg < 4; ++rg) {
                int node = nb + rg;
                if (node < NN) {
                    float v = acc[rg] + bias;
                    if (SCALE) v *= scale[node];
                    outp[(size_t)node * NH + c] = f2bf(v);
                }
            }
        }
    }
}

// ---------------- fused edge-parallel gather+relu -> MFMA GEMM ----------------
// 512 threads / 8 waves, M-tile = 64 nodes (782 blocks).
// Block edges are CONTIGUOUS in CSR (rows sorted by dst): [e_start, e_end).
// Work-items = (edge, 16B-chunk) distributed uniformly over threads: perfect
// balance, coalesced row reads. Accumulate into f32 LDS via ds_add_f32
// (unsafeAtomicAdd). Per-lane rotation of the 8-word sub-chunk spreads banks
// (else every lane writes word j -> 4 banks -> 16-way conflict).
template<int K, int NHT, bool SPLIT, bool SCALE>
__global__ __launch_bounds__(512)
void gather_gemm_k(const int* __restrict__ row_start,
                   const int* __restrict__ csr,
                   const unsigned short* __restrict__ msg,   // [NN][K] bf16
                   const unsigned short* __restrict__ hpre,  // [NN][K] bf16
                   const unsigned short* __restrict__ WT,    // [NHT][K] bf16
                   const float* __restrict__ biasHi,
                   const float* __restrict__ scale,
                   unsigned short* __restrict__ out0,
                   unsigned short* __restrict__ out1)
{
    constexpr int G   = K / 8;       // 16B chunks per row
    constexpr int KQ  = K / 4;
    constexpr int PB  = K * 2;
    constexpr int KS  = K / 32;
    constexpr int NT  = NHT / 16;
    constexpr int NTW = NT / 2;      // n-tiles per wave
    constexpr int NHh = NHT / 2;
    constexpr int CAP = 2048;        // edge-chunk capacity
    __shared__ float accs[64 * K];
    __shared__ short ablk[64 * K];
    __shared__ short wblk[NHT * K];
    __shared__ unsigned char dstb[CAP];
    const int tid = threadIdx.x;
    const int blk = blockIdx.x;
    const int rot = tid & 7;
    const int node0 = blk * 64;
    const int nval = (NN - node0 < 64) ? (NN - node0) : 64;

    // ---- phase 0a: init acc from hpre (rotated to spread banks) ----
    for (int w = tid; w < 64 * G; w += 512) {
        int r = w / G, ch = w - r * G;
        float av[8] = {0.f,0.f,0.f,0.f,0.f,0.f,0.f,0.f};
        if (r < nval) {
            uint4 h = *(const uint4*)&hpre[(size_t)(node0 + r) * K + ch * 8];
            av[0]=lof(h.x); av[1]=hif(h.x); av[2]=lof(h.y); av[3]=hif(h.y);
            av[4]=lof(h.z); av[5]=hif(h.z); av[6]=lof(h.w); av[7]=hif(h.w);
        }
        float* ap = &accs[r * K + ch * 8];
        #pragma unroll
        for (int j = 0; j < 8; ++j) { int jj = (j + rot) & 7; ap[jj] = av[jj]; }
    }
    // ---- phase 0b: stage weights (swizzled) ----
    #pragma unroll
    for (int it = 0; it < NHT * KQ / 512; ++it) {
        int idx = it * 512 + tid;
        int n = idx / KQ, c4 = idx % KQ;
        uint2 p = *(const uint2*)(WT + (size_t)n * K + c4 * 4);
        unsigned byte = (unsigned)(n * PB + c4 * 8) ^ ((unsigned)(n & 7) << 4);
        *(uint2*)((char*)wblk + byte) = p;
    }
    const int e_start = row_start[node0];
    const int e_end   = row_start[node0 + nval];
    __syncthreads();

    // ---- phase 1: edge-parallel gather (chunked by CAP) ----
    for (int base = e_start; base < e_end; base += CAP) {
        int cnt = (e_end - base < CAP) ? (e_end - base) : CAP;
        if (tid < nval) {
            int rs = row_start[node0 + tid];
            int re = row_start[node0 + tid + 1];
            rs = rs > base ? rs : base;
            re = re < base + cnt ? re : base + cnt;
            for (int e = rs; e < re; ++e) dstb[e - base] = (unsigned char)tid;
        }
        __syncthreads();
        for (int w = tid; w < cnt * G; w += 512) {
            int eL = w / G, ch = w - eL * G;
            int src = csr[base + eL];
            int r = dstb[eL];
            uint4 v = *(const uint4*)&msg[(size_t)src * K + ch * 8];
            float av[8];
            av[0]=lof(v.x); av[1]=hif(v.x); av[2]=lof(v.y); av[3]=hif(v.y);
            av[4]=lof(v.z); av[5]=hif(v.z); av[6]=lof(v.w); av[7]=hif(v.w);
            float* ap = &accs[r * K + ch * 8];
            #pragma unroll
            for (int j = 0; j < 8; ++j) {
                int jj = (j + rot) & 7;
                unsafeAtomicAdd(ap + jj, av[jj]);
            }
        }
        __syncthreads();
    }

    // ---- phase 2: relu + pack to swizzled bf16 A-tile ----
    for (int w = tid; w < 64 * G; w += 512) {
        int r = w / G, ch = w - r * G;
        float* ap = &accs[r * K + ch * 8];
        float av[8];
        #pragma unroll
        for (int j = 0; j < 8; ++j) { int jj = (j + rot) & 7; av[jj] = ap[jj]; }
        uint4 o;
        o.x = packbf(fmaxf(av[0],0.f), fmaxf(av[1],0.f));
        o.y = packbf(fmaxf(av[2],0.f), fmaxf(av[3],0.f));
        o.z = packbf(fmaxf(av[4],0.f), fmaxf(av[5],0.f));
        o.w = packbf(fmaxf(av[6],0.f), fmaxf(av[7],0.f));
        unsigned byte = (unsigned)(r * PB + ch * 16) ^ ((unsigned)(r & 7) << 4);
        *(uint4*)((char*)ablk + byte) = o;
    }
    __syncthreads();

    // ---- phase 3: MFMA. wave wv: rows (wv>>1)*16.. ; n-half wv&1 ----
    const int wv = tid >> 6, lane = tid & 63;
    const int r15 = lane & 15, g = lane >> 4;
    const int rt = wv >> 1, nth = wv & 1;

    s16x8 afr[KS];
    #pragma unroll
    for (int ks = 0; ks < KS; ++ks) {
        int r = rt * 16 + r15;
        unsigned byte = (unsigned)(r * PB + ks * 64 + g * 16) ^ ((unsigned)(r & 7) << 4);
        afr[ks] = *(const s16x8*)((char*)ablk + byte);
    }

    #pragma unroll
    for (int ntl = 0; ntl < NTW; ++ntl) {
        int nt = nth * NTW + ntl;
        s16x8 bfr[KS];
        #pragma unroll
        for (int ks = 0; ks < KS; ++ks) {
            int n = nt * 16 + r15;
            unsigned byte = (unsigned)(n * PB + ks * 64 + g * 16) ^ ((unsigned)(n & 7) << 4);
            bfr[ks] = *(const s16x8*)((char*)wblk + byte);
        }
        int c = nt * 16 + r15;
        float bias = 0.f;
        if (SPLIT && biasHi && c >= NHh) bias = biasHi[c - NHh];
        f32x4 acc = {0.f, 0.f, 0.f, 0.f};
        #pragma unroll
        for (int ks = 0; ks < KS; ++ks)
            acc = __builtin_amdgcn_mfma_f32_16x16x32_bf16(afr[ks], bfr[ks], acc, 0, 0, 0);
        int nb = node0 + rt * 16 + g * 4;
        #pragma unroll
        for (int rg = 0; rg < 4; ++rg) {
            int node = nb + rg;
            if (node < NN) {
                float v = acc[rg] + bias;
                if (SCALE) v *= scale[node];
                if (SPLIT) {
                    if (c < NHh) out0[(size_t)node * NHh + c] = f2bf(v);
                    else         out1[(size_t)node * NHh + (c - NHh)] = f2bf(v);
                } else {
                    out0[(size_t)node * NHT + c] = f2bf(v);
                }
            }
        }
    }
}

// ---------------- GCN gather (edge-split-2): out = dinv_i*(y_i + sum y_j)+b --
__global__ __launch_bounds__(256)
void gather_gcn_k(const int* __restrict__ row_start,
                  const int* __restrict__ csr,
                  const unsigned short* __restrict__ y,   // bf16, pre-scaled by dinv
                  const float* __restrict__ dinv,
                  const float* __restrict__ b_mu,
                  const float* __restrict__ b_ls,
                  float* __restrict__ out)
{
    int idx = blockIdx.x * 256 + threadIdx.x;    // NN*16 exact (3125 blocks)
    int i   = idx >> 4;
    int rem = idx & 15;
    int ch = rem >> 1, sub = rem & 1;
    int c8 = ch * 8;
    float a[8] = {0.f,0.f,0.f,0.f,0.f,0.f,0.f,0.f};
    if (sub == 0) {
        uint4 h = *(const uint4*)&y[(size_t)i * 64 + c8];
        a[0] = lof(h.x); a[1] = hif(h.x); a[2] = lof(h.y); a[3] = hif(h.y);
        a[4] = lof(h.z); a[5] = hif(h.z); a[6] = lof(h.w); a[7] = hif(h.w);
    }
    int e0 = row_start[i], e1 = row_start[i + 1];
    int e = e0 + sub;
    for (; e + 2 < e1; e += 4) {
        int s0 = csr[e], s1 = csr[e + 2];
        uint4 v0 = *(const uint4*)&y[(size_t)s0 * 64 + c8];
        uint4 v1 = *(const uint4*)&y[(size_t)s1 * 64 + c8];
        a[0] += lof(v0.x); a[1] += hif(v0.x); a[2] += lof(v0.y); a[3] += hif(v0.y);
        a[4] += lof(v0.z); a[5] += hif(v0.z); a[6] += lof(v0.w); a[7] += hif(v0.w);
        a[0] += lof(v1.x); a[1] += hif(v1.x); a[2] += lof(v1.y); a[3] += hif(v1.y);
        a[4] += lof(v1.z); a[5] += hif(v1.z); a[6] += lof(v1.w); a[7] += hif(v1.w);
    }
    if (e < e1) {
        int s = csr[e];
        uint4 v = *(const uint4*)&y[(size_t)s * 64 + c8];
        a[0] += lof(v.x); a[1] += hif(v.x); a[2] += lof(v.y); a[3] += hif(v.y);
        a[4] += lof(v.z); a[5] += hif(v.z); a[6] += lof(v.w); a[7] += hif(v.w);
    }
    #pragma unroll
    for (int q = 0; q < 8; ++q) a[q] += __shfl_xor(a[q], 1);
    if (sub) return;
    float di = dinv[i];
    const float* b;
    float* o;
    if (c8 < 32) { b = &b_mu[c8];      o = &out[(size_t)i * 32 + c8]; }
    else         { b = &b_ls[c8 - 32]; o = &out[(size_t)NN * 32 + (size_t)i * 32 + (c8 - 32)]; }
    float4 r0, r1;
    r0.x = di * a[0] + b[0]; r0.y = di * a[1] + b[1];
    r0.z = di * a[2] + b[2]; r0.w = di * a[3] + b[3];
    r1.x = di * a[4] + b[4]; r1.y = di * a[5] + b[5];
    r1.z = di * a[6] + b[6]; r1.w = di * a[7] + b[7];
    *(float4*)&o[0] = r0;
    *(float4*)&o[4] = r1;
}

extern "C" void kernel_launch(void* const* d_in, const int* in_sizes, int n_in,
                              void* d_out, int out_size, void* d_ws, size_t ws_size,
                              hipStream_t stream)
{
    (void)in_sizes; (void)n_in; (void)out_size; (void)ws_size;
    const float* x       = (const float*)d_in[0];
    const int*   ei      = (const int*)d_in[1];
    const int*   srcv    = ei;
    const int*   dstv    = ei + NE;
    const float* w1_rel  = (const float*)d_in[2];
    const float* w1_root = (const float*)d_in[3];
    const float* b1      = (const float*)d_in[4];
    const float* w2_rel  = (const float*)d_in[5];
    const float* w2_root = (const float*)d_in[6];
    const float* b2      = (const float*)d_in[7];
    const float* w_mu    = (const float*)d_in[8];
    const float* b_mu    = (const float*)d_in[9];
    const float* w_ls    = (const float*)d_in[10];
    const float* b_ls    = (const float*)d_in[11];
    float* out = (float*)d_out;

    char* ws = (char*)d_ws;
    unsigned short* t1    = (unsigned short*)(ws);              // 9.6MB  NN*96 bf16
    unsigned short* h1pre = (unsigned short*)(ws + 9600000);    // 9.6MB
    unsigned short* t2    = (unsigned short*)(ws + 19200000);   // 6.4MB  NN*64 bf16
    unsigned short* h2pre = (unsigned short*)(ws + 25600000);   // 6.4MB
    unsigned short* y     = (unsigned short*)(ws + 32000000);   // 6.4MB
    int* csr       = (int*)(ws + 38400000);                     // 2.4MB
    int* row_start = (int*)(ws + 40800000);                     // (NN+1)*4
    int* cursor    = (int*)(ws + 41000016);                     // NN*4
    float* dinv    = (float*)(ws + 41200016);                   // NN*4
    int* deg       = (int*)(ws + 41400016);                     // NN*4
    int* partial   = (int*)(ws + 41600016);                     // NB*4
    unsigned short* wt1 = (unsigned short*)(ws + 41700016);     // 192*128*2
    unsigned short* wt2 = (unsigned short*)(ws + 41749168);     // 128*96*2
    unsigned short* wt3 = (unsigned short*)(ws + 41773744);     // 64*64*2

    // ---- CSR build + norm + weight prep ----
    zero_wprep_k<<<NB, 256, 0, stream>>>(deg, w1_rel, w1_root, w2_rel, w2_root,
                                         w_mu, w_ls, wt1, wt2, wt3);
    count_deg_k<<<(NE + 255) / 256, 256, 0, stream>>>(dstv, deg);
    scan_reduce_k<<<NB, 256, 0, stream>>>(deg, partial);
    scan_final2_k<<<NB, 256, 0, stream>>>(deg, partial, row_start, cursor, dinv);
    fill_k<<<(NE + 255) / 256, 256, 0, stream>>>(srcv, dstv, cursor, csr);

    // ---- layer 1: t1 = x@w1_rel ; h1pre = x@w1_root + b1 ----
    gemm_mfma<128, 96, false, false><<<dim3(391, 2), 256, 0, stream>>>(
        x, wt1, b1, nullptr, t1, h1pre);

    // ---- layer 2 (fused): h1 = relu(h1pre + gather t1) in LDS (f32 acc);
    //      t2 = h1@w2_rel ; h2pre = h1@w2_root + b2 ----
    gather_gemm_k<96, 128, true, false><<<782, 512, 0, stream>>>(
        row_start, csr, t1, h1pre, wt2, b2, nullptr, t2, h2pre);

    // ---- layer 3 (fused): h2 = relu(h2pre + gather t2) in LDS;
    //      y = dinv * (h2 @ [w_mu | w_ls]) ----
    gather_gemm_k<64, 64, false, true><<<782, 512, 0, stream>>>(
        row_start, csr, t2, h2pre, wt3, nullptr, dinv, y, nullptr);

    // ---- GCN aggregate + bias -> out ----
    gather_gcn_k<<<(NN * 16) / 256, 256, 0, stream>>>(row_start, csr, y, dinv, b_mu, b_ls, out);
}

// Round 11
// 160.397 us; speedup vs baseline: 4.7616x; 4.7616x over previous
//
#include <hip/hip_runtime.h>
#include <cstddef>

static constexpr int NN = 50000;
static constexpr int NE = 600000;
static constexpr int NB = (NN + 255) / 256;   // 196 scan blocks

using f32x4 = __attribute__((ext_vector_type(4))) float;
using s16x8 = __attribute__((ext_vector_type(8))) short;

// ---------------- bf16 helpers (manual, RNE) ----------------
__device__ inline float bf2f(unsigned short u) {
    return __uint_as_float(((unsigned)u) << 16);
}
__device__ inline unsigned short f2bf(float f) {
    unsigned u = __float_as_uint(f);
    unsigned r = u + 0x7fffu + ((u >> 16) & 1u);
    return (unsigned short)(r >> 16);
}
__device__ inline float lof(unsigned u) { return __uint_as_float(u << 16); }
__device__ inline float hif(unsigned u) { return __uint_as_float(u & 0xffff0000u); }
__device__ inline unsigned packbf(float a, float b) {
    return (unsigned)f2bf(a) | ((unsigned)f2bf(b) << 16);
}

// ---------------- zero deg + weight transpose/bf16 prepass (fused) ----------
__global__ __launch_bounds__(256)
void zero_wprep_k(int* __restrict__ deg,
                  const float* __restrict__ w1_rel, const float* __restrict__ w1_root,
                  const float* __restrict__ w2_rel, const float* __restrict__ w2_root,
                  const float* __restrict__ w_mu,   const float* __restrict__ w_ls,
                  unsigned short* __restrict__ wt1, unsigned short* __restrict__ wt2,
                  unsigned short* __restrict__ wt3)
{
    int i = blockIdx.x * 256 + threadIdx.x;
    if (i < NN) deg[i] = 0;
    if (i < 24576) {                       // WT1: K=128, N=192
        int k = i / 192, n = i % 192;
        float v = (n < 96) ? w1_rel[k * 96 + n] : w1_root[k * 96 + (n - 96)];
        wt1[n * 128 + k] = f2bf(v);
    } else if (i < 36864) {                // WT2: K=96, N=128
        int j = i - 24576;
        int k = j / 128, n = j % 128;
        float v = (n < 64) ? w2_rel[k * 64 + n] : w2_root[k * 64 + (n - 64)];
        wt2[n * 96 + k] = f2bf(v);
    } else if (i < 40960) {                // WT3: K=64, N=64
        int j = i - 36864;
        int k = j / 64, n = j % 64;
        float v = (n < 32) ? w_mu[k * 32 + n] : w_ls[k * 32 + (n - 32)];
        wt3[n * 64 + k] = f2bf(v);
    }
}

// ---------------- degree count ----------------
__global__ __launch_bounds__(256)
void count_deg_k(const int* __restrict__ dstv, int* __restrict__ deg) {
    int e = blockIdx.x * 256 + threadIdx.x;
    if (e < NE) atomicAdd(&deg[dstv[e]], 1);
}

// ---------------- scan: per-block reduce -> partial ----------------
__global__ __launch_bounds__(256)
void scan_reduce_k(const int* __restrict__ deg, int* __restrict__ partial) {
    __shared__ int buf[256];
    int i = blockIdx.x * 256 + threadIdx.x;
    buf[threadIdx.x] = (i < NN) ? deg[i] : 0;
    __syncthreads();
    #pragma unroll
    for (int off = 128; off > 0; off >>= 1) {
        if (threadIdx.x < off) buf[threadIdx.x] += buf[threadIdx.x + off];
        __syncthreads();
    }
    if (threadIdx.x == 0) partial[blockIdx.x] = buf[0];
}

// ---------------- scan final: each block scans partials itself ----------------
__global__ __launch_bounds__(256)
void scan_final2_k(const int* __restrict__ deg, const int* __restrict__ partial,
                   int* __restrict__ row_start, int* __restrict__ cursor,
                   float* __restrict__ dinv) {
    __shared__ int pb[256], po[256], buf[256];
    int t = threadIdx.x;
    int pv = (t < NB) ? partial[t] : 0;
    pb[t] = pv; po[t] = pv;
    __syncthreads();
    #pragma unroll
    for (int off = 1; off < 256; off <<= 1) {
        int tv = (t >= off) ? pb[t - off] : 0;
        __syncthreads();
        pb[t] += tv;
        __syncthreads();
    }
    int i = blockIdx.x * 256 + t;
    int v = (i < NN) ? deg[i] : 0;
    buf[t] = v;
    __syncthreads();
    #pragma unroll
    for (int off = 1; off < 256; off <<= 1) {
        int tv = (t >= off) ? buf[t - off] : 0;
        __syncthreads();
        buf[t] += tv;
        __syncthreads();
    }
    int blkoff = pb[blockIdx.x] - po[blockIdx.x];   // exclusive offset of this block
    if (i < NN) {
        int pos = blkoff + buf[t] - v;
        row_start[i] = pos;
        cursor[i] = pos;
        dinv[i] = rsqrtf((float)v + 1.0f);          // +1 self-loop
    }
    if (blockIdx.x == 0 && t == 0) row_start[NN] = pb[NB - 1];   // == NE
}

// ---------------- CSR fill ----------------
__global__ __launch_bounds__(256)
void fill_k(const int* __restrict__ srcv, const int* __restrict__ dstv,
            int* __restrict__ cursor, int* __restrict__ csr)
{
    int e = blockIdx.x * 256 + threadIdx.x;
    if (e < NE) {
        int pos = atomicAdd(&cursor[dstv[e]], 1);
        csr[pos] = srcv[e];
    }
}

// ---------------- MFMA GEMM (layer 1, dense input) ----------------
template<int K, int NH, bool XB, bool SCALE>
__global__ __launch_bounds__(256)
void gemm_mfma(const void* __restrict__ Xv,
               const unsigned short* __restrict__ WT,
               const float* __restrict__ biasB,
               const float* __restrict__ scale,
               unsigned short* __restrict__ out0,
               unsigned short* __restrict__ out1)
{
    constexpr int KQ = K / 4;
    constexpr int PB = K * 2;
    constexpr int KS = K / 32;
    constexpr int NT = NH / 16;
    __shared__ short lds[(128 + NH) * K];
    char* ldsb = (char*)lds;
    const int tid = threadIdx.x;
    const int blk = blockIdx.x;
    const int half = blockIdx.y;

    const unsigned short* wt = WT + (size_t)half * NH * K;
    unsigned short* outp = half ? out1 : out0;

    #pragma unroll
    for (int it = 0; it < KQ / 2; ++it) {
        int idx = it * 256 + tid;
        int r = idx / KQ, c4 = idx % KQ;
        int node = blk * 128 + r; if (node >= NN) node = NN - 1;
        uint2 p;
        if (XB) {
            p = *(const uint2*)((const unsigned short*)Xv + (size_t)node * K + c4 * 4);
        } else {
            float4 v = *(const float4*)((const float*)Xv + (size_t)node * K + c4 * 4);
            p.x = packbf(v.x, v.y); p.y = packbf(v.z, v.w);
        }
        unsigned byte = (unsigned)(r * PB + c4 * 8) ^ ((unsigned)(r & 7) << 4);
        *(uint2*)(ldsb + byte) = p;
    }
    #pragma unroll
    for (int it = 0; it < NH * KQ / 256; ++it) {
        int idx = it * 256 + tid;
        int n = idx / KQ, c4 = idx % KQ;
        uint2 p = *(const uint2*)(wt + (size_t)n * K + c4 * 4);
        int pr = 128 + n;
        unsigned byte = (unsigned)(pr * PB + c4 * 8) ^ ((unsigned)(pr & 7) << 4);
        *(uint2*)(ldsb + byte) = p;
    }
    __syncthreads();

    const int wv = tid >> 6, lane = tid & 63;
    const int r15 = lane & 15, g = lane >> 4;

    s16x8 afr[2][KS];
    #pragma unroll
    for (int ms = 0; ms < 2; ++ms) {
        #pragma unroll
        for (int ks = 0; ks < KS; ++ks) {
            int r = wv * 32 + ms * 16 + r15;
            unsigned byte = (unsigned)(r * PB + ks * 64 + g * 16) ^ ((unsigned)(r & 7) << 4);
            afr[ms][ks] = *(const s16x8*)(ldsb + byte);
        }
    }

    #pragma unroll
    for (int nt = 0; nt < NT; ++nt) {
        s16x8 bfr[KS];
        #pragma unroll
        for (int ks = 0; ks < KS; ++ks) {
            int pr = 128 + nt * 16 + r15;
            unsigned byte = (unsigned)(pr * PB + ks * 64 + g * 16) ^ ((unsigned)(pr & 7) << 4);
            bfr[ks] = *(const s16x8*)(ldsb + byte);
        }
        int c = nt * 16 + r15;
        float bias = (half && biasB) ? biasB[c] : 0.f;
        #pragma unroll
        for (int ms = 0; ms < 2; ++ms) {
            f32x4 acc = {0.f, 0.f, 0.f, 0.f};
            #pragma unroll
            for (int ks = 0; ks < KS; ++ks)
                acc = __builtin_amdgcn_mfma_f32_16x16x32_bf16(afr[ms][ks], bfr[ks], acc, 0, 0, 0);
            int nb = blk * 128 + wv * 32 + ms * 16 + g * 4;
            #pragma unroll
            for (int rg = 0; rg < 4; ++rg) {
                int node = nb + rg;
                if (node < NN) {
                    float v = acc[rg] + bias;
                    if (SCALE) v *= scale[node];
                    outp[(size_t)node * NH + c] = f2bf(v);
                }
            }
        }
    }
}

// ---------------- fused gather+relu -> LDS A-tile -> MFMA GEMM ----------------
// 512 threads / 8 waves. M-tile = 64 nodes (782 blocks).
// Edge-split-2: two adjacent lanes share one (row, chunk), covering even/odd
// edges; combined via __shfl_xor(.,1). Halves max-degree serialization and
// doubles loads-in-flight. MFMA phase: wave wv -> rows (wv>>1)*16, N-half wv&1.
template<int K, int NHT, bool SPLIT, bool SCALE>
__global__ __launch_bounds__(512)
void gather_gemm_k(const int* __restrict__ row_start,
                   const int* __restrict__ csr,
                   const unsigned short* __restrict__ msg,   // [NN][K] bf16
                   const unsigned short* __restrict__ hpre,  // [NN][K] bf16
                   const unsigned short* __restrict__ WT,    // [NHT][K] bf16
                   const float* __restrict__ biasHi,
                   const float* __restrict__ scale,
                   unsigned short* __restrict__ out0,
                   unsigned short* __restrict__ out1)
{
    constexpr int G   = K / 8;
    constexpr int G2  = G * 2;       // threads per row (edge-split-2)
    constexpr int KQ  = K / 4;
    constexpr int PB  = K * 2;
    constexpr int KS  = K / 32;
    constexpr int NT  = NHT / 16;
    constexpr int NTW = NT / 2;      // n-tiles per wave
    constexpr int NHh = NHT / 2;
    __shared__ short lds[(64 + NHT) * K];
    char* ldsb = (char*)lds;
    const int tid = threadIdx.x;
    const int blk = blockIdx.x;

    // ---- phase 1: gather+relu rows into LDS A-tile ----
    for (int it = 0; it < 64 * G2 / 512; ++it) {
        int w = it * 512 + tid;
        int r = w / G2;
        int rem = w - r * G2;
        int ch = rem >> 1, sub = rem & 1;
        int c8 = ch * 8;
        int node = blk * 64 + r;
        float a[8] = {0.f,0.f,0.f,0.f,0.f,0.f,0.f,0.f};
        if (node < NN) {
            if (sub == 0) {
                uint4 h = *(const uint4*)&hpre[(size_t)node * K + c8];
                a[0] = lof(h.x); a[1] = hif(h.x); a[2] = lof(h.y); a[3] = hif(h.y);
                a[4] = lof(h.z); a[5] = hif(h.z); a[6] = lof(h.w); a[7] = hif(h.w);
            }
            int e0 = row_start[node], e1 = row_start[node + 1];
            int e = e0 + sub;
            for (; e + 2 < e1; e += 4) {
                int s0 = csr[e], s1 = csr[e + 2];
                uint4 v0 = *(const uint4*)&msg[(size_t)s0 * K + c8];
                uint4 v1 = *(const uint4*)&msg[(size_t)s1 * K + c8];
                a[0] += lof(v0.x); a[1] += hif(v0.x); a[2] += lof(v0.y); a[3] += hif(v0.y);
                a[4] += lof(v0.z); a[5] += hif(v0.z); a[6] += lof(v0.w); a[7] += hif(v0.w);
                a[0] += lof(v1.x); a[1] += hif(v1.x); a[2] += lof(v1.y); a[3] += hif(v1.y);
                a[4] += lof(v1.z); a[5] += hif(v1.z); a[6] += lof(v1.w); a[7] += hif(v1.w);
            }
            if (e < e1) {
                int s = csr[e];
                uint4 v = *(const uint4*)&msg[(size_t)s * K + c8];
                a[0] += lof(v.x); a[1] += hif(v.x); a[2] += lof(v.y); a[3] += hif(v.y);
                a[4] += lof(v.z); a[5] += hif(v.z); a[6] += lof(v.w); a[7] += hif(v.w);
            }
        }
        #pragma unroll
        for (int q = 0; q < 8; ++q) {
            a[q] += __shfl_xor(a[q], 1);
            a[q] = fmaxf(a[q], 0.f);
        }
        if (sub == 0) {
            uint4 o;
            o.x = packbf(a[0], a[1]); o.y = packbf(a[2], a[3]);
            o.z = packbf(a[4], a[5]); o.w = packbf(a[6], a[7]);
            unsigned byte = (unsigned)(r * PB + ch * 16) ^ ((unsigned)(r & 7) << 4);
            *(uint4*)(ldsb + byte) = o;
        }
    }
    // ---- phase 1b: stage weights ----
    #pragma unroll
    for (int it = 0; it < NHT * KQ / 512; ++it) {
        int idx = it * 512 + tid;
        int n = idx / KQ, c4 = idx % KQ;
        uint2 p = *(const uint2*)(WT + (size_t)n * K + c4 * 4);
        int pr = 64 + n;
        unsigned byte = (unsigned)(pr * PB + c4 * 8) ^ ((unsigned)(pr & 7) << 4);
        *(uint2*)(ldsb + byte) = p;
    }
    __syncthreads();

    // ---- phase 2: MFMA. wave wv: rows (wv>>1)*16.. ; n-half wv&1 ----
    const int wv = tid >> 6, lane = tid & 63;
    const int r15 = lane & 15, g = lane >> 4;
    const int rt = wv >> 1, nth = wv & 1;

    s16x8 afr[KS];
    #pragma unroll
    for (int ks = 0; ks < KS; ++ks) {
        int r = rt * 16 + r15;
        unsigned byte = (unsigned)(r * PB + ks * 64 + g * 16) ^ ((unsigned)(r & 7) << 4);
        afr[ks] = *(const s16x8*)(ldsb + byte);
    }

    #pragma unroll
    for (int ntl = 0; ntl < NTW; ++ntl) {
        int nt = nth * NTW + ntl;
        s16x8 bfr[KS];
        #pragma unroll
        for (int ks = 0; ks < KS; ++ks) {
            int pr = 64 + nt * 16 + r15;
            unsigned byte = (unsigned)(pr * PB + ks * 64 + g * 16) ^ ((unsigned)(pr & 7) << 4);
            bfr[ks] = *(const s16x8*)(ldsb + byte);
        }
        int c = nt * 16 + r15;
        float bias = 0.f;
        if (SPLIT && biasHi && c >= NHh) bias = biasHi[c - NHh];
        f32x4 acc = {0.f, 0.f, 0.f, 0.f};
        #pragma unroll
        for (int ks = 0; ks < KS; ++ks)
            acc = __builtin_amdgcn_mfma_f32_16x16x32_bf16(afr[ks], bfr[ks], acc, 0, 0, 0);
        int nb = blk * 64 + rt * 16 + g * 4;
        #pragma unroll
        for (int rg = 0; rg < 4; ++rg) {
            int node = nb + rg;
            if (node < NN) {
                float v = acc[rg] + bias;
                if (SCALE) v *= scale[node];
                if (SPLIT) {
                    if (c < NHh) out0[(size_t)node * NHh + c] = f2bf(v);
                    else         out1[(size_t)node * NHh + (c - NHh)] = f2bf(v);
                } else {
                    out0[(size_t)node * NHT + c] = f2bf(v);
                }
            }
        }
    }
}

// ---------------- GCN gather (edge-split-2): out = dinv_i*(y_i + sum y_j)+b --
__global__ __launch_bounds__(256)
void gather_gcn_k(const int* __restrict__ row_start,
                  const int* __restrict__ csr,
                  const unsigned short* __restrict__ y,   // bf16, pre-scaled by dinv
                  const float* __restrict__ dinv,
                  const float* __restrict__ b_mu,
                  const float* __restrict__ b_ls,
                  float* __restrict__ out)
{
    int idx = blockIdx.x * 256 + threadIdx.x;    // NN*16 exact (3125 blocks)
    int i   = idx >> 4;
    int rem = idx & 15;
    int ch = rem >> 1, sub = rem & 1;
    int c8 = ch * 8;
    float a[8] = {0.f,0.f,0.f,0.f,0.f,0.f,0.f,0.f};
    if (sub == 0) {
        uint4 h = *(const uint4*)&y[(size_t)i * 64 + c8];
        a[0] = lof(h.x); a[1] = hif(h.x); a[2] = lof(h.y); a[3] = hif(h.y);
        a[4] = lof(h.z); a[5] = hif(h.z); a[6] = lof(h.w); a[7] = hif(h.w);
    }
    int e0 = row_start[i], e1 = row_start[i + 1];
    int e = e0 + sub;
    for (; e + 2 < e1; e += 4) {
        int s0 = csr[e], s1 = csr[e + 2];
        uint4 v0 = *(const uint4*)&y[(size_t)s0 * 64 + c8];
        uint4 v1 = *(const uint4*)&y[(size_t)s1 * 64 + c8];
        a[0] += lof(v0.x); a[1] += hif(v0.x); a[2] += lof(v0.y); a[3] += hif(v0.y);
        a[4] += lof(v0.z); a[5] += hif(v0.z); a[6] += lof(v0.w); a[7] += hif(v0.w);
        a[0] += lof(v1.x); a[1] += hif(v1.x); a[2] += lof(v1.y); a[3] += hif(v1.y);
        a[4] += lof(v1.z); a[5] += hif(v1.z); a[6] += lof(v1.w); a[7] += hif(v1.w);
    }
    if (e < e1) {
        int s = csr[e];
        uint4 v = *(const uint4*)&y[(size_t)s * 64 + c8];
        a[0] += lof(v.x); a[1] += hif(v.x); a[2] += lof(v.y); a[3] += hif(v.y);
        a[4] += lof(v.z); a[5] += hif(v.z); a[6] += lof(v.w); a[7] += hif(v.w);
    }
    #pragma unroll
    for (int q = 0; q < 8; ++q) a[q] += __shfl_xor(a[q], 1);
    if (sub) return;
    float di = dinv[i];
    const float* b;
    float* o;
    if (c8 < 32) { b = &b_mu[c8];      o = &out[(size_t)i * 32 + c8]; }
    else         { b = &b_ls[c8 - 32]; o = &out[(size_t)NN * 32 + (size_t)i * 32 + (c8 - 32)]; }
    float4 r0, r1;
    r0.x = di * a[0] + b[0]; r0.y = di * a[1] + b[1];
    r0.z = di * a[2] + b[2]; r0.w = di * a[3] + b[3];
    r1.x = di * a[4] + b[4]; r1.y = di * a[5] + b[5];
    r1.z = di * a[6] + b[6]; r1.w = di * a[7] + b[7];
    *(float4*)&o[0] = r0;
    *(float4*)&o[4] = r1;
}

extern "C" void kernel_launch(void* const* d_in, const int* in_sizes, int n_in,
                              void* d_out, int out_size, void* d_ws, size_t ws_size,
                              hipStream_t stream)
{
    (void)in_sizes; (void)n_in; (void)out_size; (void)ws_size;
    const float* x       = (const float*)d_in[0];
    const int*   ei      = (const int*)d_in[1];
    const int*   srcv    = ei;
    const int*   dstv    = ei + NE;
    const float* w1_rel  = (const float*)d_in[2];
    const float* w1_root = (const float*)d_in[3];
    const float* b1      = (const float*)d_in[4];
    const float* w2_rel  = (const float*)d_in[5];
    const float* w2_root = (const float*)d_in[6];
    const float* b2      = (const float*)d_in[7];
    const float* w_mu    = (const float*)d_in[8];
    const float* b_mu    = (const float*)d_in[9];
    const float* w_ls    = (const float*)d_in[10];
    const float* b_ls    = (const float*)d_in[11];
    float* out = (float*)d_out;

    char* ws = (char*)d_ws;
    unsigned short* t1    = (unsigned short*)(ws);              // 9.6MB  NN*96 bf16
    unsigned short* h1pre = (unsigned short*)(ws + 9600000);    // 9.6MB
    unsigned short* t2    = (unsigned short*)(ws + 19200000);   // 6.4MB  NN*64 bf16
    unsigned short* h2pre = (unsigned short*)(ws + 25600000);   // 6.4MB
    unsigned short* y     = (unsigned short*)(ws + 32000000);   // 6.4MB
    int* csr       = (int*)(ws + 38400000);                     // 2.4MB
    int* row_start = (int*)(ws + 40800000);                     // (NN+1)*4
    int* cursor    = (int*)(ws + 41000016);                     // NN*4
    float* dinv    = (float*)(ws + 41200016);                   // NN*4
    int* deg       = (int*)(ws + 41400016);                     // NN*4
    int* partial   = (int*)(ws + 41600016);                     // NB*4
    unsigned short* wt1 = (unsigned short*)(ws + 41700016);     // 192*128*2
    unsigned short* wt2 = (unsigned short*)(ws + 41749168);     // 128*96*2
    unsigned short* wt3 = (unsigned short*)(ws + 41773744);     // 64*64*2

    // ---- CSR build + norm + weight prep ----
    zero_wprep_k<<<NB, 256, 0, stream>>>(deg, w1_rel, w1_root, w2_rel, w2_root,
                                         w_mu, w_ls, wt1, wt2, wt3);
    count_deg_k<<<(NE + 255) / 256, 256, 0, stream>>>(dstv, deg);
    scan_reduce_k<<<NB, 256, 0, stream>>>(deg, partial);
    scan_final2_k<<<NB, 256, 0, stream>>>(deg, partial, row_start, cursor, dinv);
    fill_k<<<(NE + 255) / 256, 256, 0, stream>>>(srcv, dstv, cursor, csr);

    // ---- layer 1: t1 = x@w1_rel ; h1pre = x@w1_root + b1 ----
    gemm_mfma<128, 96, false, false><<<dim3(391, 2), 256, 0, stream>>>(
        x, wt1, b1, nullptr, t1, h1pre);

    // ---- layer 2 (fused): h1 = relu(h1pre + gather t1) in LDS;
    //      t2 = h1@w2_rel ; h2pre = h1@w2_root + b2 ----
    gather_gemm_k<96, 128, true, false><<<782, 512, 0, stream>>>(
        row_start, csr, t1, h1pre, wt2, b2, nullptr, t2, h2pre);

    // ---- layer 3 (fused): h2 = relu(h2pre + gather t2) in LDS;
    //      y = dinv * (h2 @ [w_mu | w_ls]) ----
    gather_gemm_k<64, 64, false, true><<<782, 512, 0, stream>>>(
        row_start, csr, t2, h2pre, wt3, nullptr, dinv, y, nullptr);

    // ---- GCN aggregate + bias -> out ----
    gather_gcn_k<<<(NN * 16) / 256, 256, 0, stream>>>(row_start, csr, y, dinv, b_mu, b_ls, out);
}